// Round 6
// baseline (772.601 us; speedup 1.0000x reference)
//
#include <hip/hip_runtime.h>
#include <hip/hip_bf16.h>

namespace {

constexpr int B = 2;
constexpr int N = 40000;
constexpr int E = 400000;
constexpr int R = 64;
constexpr int D = 64;
constexpr int L = 6;
constexpr float EPS = 1e-5f;
constexpr int NB = (N + 255) / 256;   // 157 node-grid blocks
constexpr int EB = (E + 255) / 256;   // 1563 edge-grid blocks

// Compiler-only memory barrier: blocks TBAA-based reordering of the
// float4-cast LDS reads above the float2-typed LDS writes (runtime LDS
// ordering within a wave is already in-order; this is compile-time insurance).
__device__ __forceinline__ void compiler_fence() { asm volatile("" ::: "memory"); }

// Batch-interleaved layout: float2 element = (batch0, batch1).

// ---- query gather + boundary scatter (x must be pre-zeroed) ----
__global__ void k_init(const float* __restrict__ rel_reps,
                       const int* __restrict__ h_index, const int* __restrict__ r_index,
                       float* __restrict__ x_f, float* __restrict__ query_f) {
  int t = threadIdx.x;           // 128 threads
  int b = t >> 6, d = t & 63;
  float q = rel_reps[(b * R + r_index[b]) * D + d];
  query_f[d * 2 + b] = q;
  x_f[((size_t)h_index[b] * D + d) * 2 + b] = q;
}

// ---- relation projection MLP for all layers: rel2[l][r*64+d] = (b0, b1) ----
__global__ __launch_bounds__(64) void k_rel(
    const float* __restrict__ rel_reps,
    const float* __restrict__ pw1, const float* __restrict__ pb1,
    const float* __restrict__ pw2, const float* __restrict__ pb2,
    float* __restrict__ rel_f) {
  __shared__ float row[D];
  __shared__ float row2[D];
  int idx = blockIdx.x;             // [0, L*B*R)
  int l = idx / (B * R);
  int br = idx - l * (B * R);       // b*R + r
  int b = br / R, r = br - b * R;
  int d = threadIdx.x;
  row[d] = rel_reps[(size_t)br * D + d];
  __syncthreads();
  const float* w1 = pw1 + (size_t)l * D * D;
  float acc = pb1[l * D + d];
  for (int k = 0; k < D; ++k) acc = fmaf(row[k], w1[k * D + d], acc);
  row2[d] = fmaxf(acc, 0.f);
  __syncthreads();
  const float* w2 = pw2 + (size_t)l * D * D;
  float acc2 = pb2[l * D + d];
  for (int k = 0; k < D; ++k) acc2 = fmaf(row2[k], w2[k * D + d], acc2);
  rel_f[(((size_t)l * R + r) * D + d) * 2 + b] = acc2;
}

// ---- CSR build ----
__global__ __launch_bounds__(256) void k_hist(const int* __restrict__ dst,
                                              int* __restrict__ cnt) {
  int e = blockIdx.x * 256 + threadIdx.x;
  if (e < E) atomicAdd(&cnt[dst[e]], 1);
}

// pass 1: per-block exclusive scan (into row_ptr as scratch) + block sums
__global__ __launch_bounds__(256) void k_scan1(const int* __restrict__ cnt,
                                               int* __restrict__ row_ptr,
                                               int* __restrict__ bsum) {
  __shared__ int s[256];
  int t = threadIdx.x;
  int i = blockIdx.x * 256 + t;
  int v = (i < N) ? cnt[i] : 0;
  s[t] = v;
  __syncthreads();
  #pragma unroll
  for (int off = 1; off < 256; off <<= 1) {   // Hillis-Steele inclusive
    int u = (t >= off) ? s[t - off] : 0;
    __syncthreads();
    s[t] += u;
    __syncthreads();
  }
  if (i < N) row_ptr[i] = s[t] - v;           // exclusive-in-block
  if (t == 255) bsum[blockIdx.x] = s[255];
}

// pass 2: scan the 157 block sums (tiny, in LDS)
__global__ __launch_bounds__(256) void k_scan2(int* __restrict__ bsum,
                                               int* __restrict__ row_ptr) {
  __shared__ int s[NB];
  int t = threadIdx.x;
  if (t < NB) s[t] = bsum[t];
  __syncthreads();
  if (t == 0) {
    int run = 0;
    for (int i = 0; i < NB; ++i) { int v = s[i]; s[i] = run; run += v; }
    row_ptr[N] = run;                         // = E
  }
  __syncthreads();
  if (t < NB) bsum[t] = s[t];
}

// pass 3: add block offsets; also init cursor
__global__ __launch_bounds__(256) void k_scan3(int* __restrict__ row_ptr,
                                               const int* __restrict__ bsum,
                                               int* __restrict__ cursor) {
  int i = blockIdx.x * 256 + threadIdx.x;
  if (i < N) {
    int v = row_ptr[i] + bsum[blockIdx.x];
    row_ptr[i] = v;
    cursor[i] = v;
  }
}

__global__ __launch_bounds__(256) void k_fill(const int* __restrict__ src,
                                              const int* __restrict__ dst,
                                              const int* __restrict__ etype,
                                              int* __restrict__ cursor,
                                              unsigned int* __restrict__ es) {
  int e = blockIdx.x * 256 + threadIdx.x;
  if (e < E) {
    int p = atomicAdd(&cursor[dst[e]], 1);
    es[p] = (unsigned int)src[e] | ((unsigned int)etype[e] << 16);  // src < 65536
  }
}

// ---- fused layer: CSR gather + boundary + linear + LN + relu + shortcut ----
// 512 threads = 8 waves; 8 nodes/wave as 2 groups of 4; 625 blocks.
// Linear phase amortizes weight LDS reads over 4 nodes (k-paired fp32 weights).
__global__ __launch_bounds__(512, 4) void k_layer(
    const float2* __restrict__ xo, float2* __restrict__ xn,
    const float2* __restrict__ rel2,             // [R*64] float2, this layer
    const int* __restrict__ row_ptr, const unsigned int* __restrict__ es,
    const float2* __restrict__ q2, const int* __restrict__ h_index,
    const float* __restrict__ lin_w, const float* __restrict__ lin_b,
    const float* __restrict__ ln_g, const float* __restrict__ ln_b,
    int layer, int first) {
  __shared__ float2 wpk[D][D];         // wpk[k2][out] = (w[2k2][out], w[2k2+1][out]), 32 KB
  __shared__ float bias_s[D], g_s[D], b_s[D];
  __shared__ float2 rows[8][4][2 * D]; // per-wave, 4 nodes, concat row; 32 KB
  int tid = threadIdx.x;
  const float* lw = lin_w + (size_t)layer * 2 * D * D;
  for (int i = tid; i < D * D; i += 512) {
    int k2 = i >> 6, out = i & 63;
    wpk[k2][out] = make_float2(lw[(2 * k2) * D + out], lw[(2 * k2 + 1) * D + out]);
  }
  if (tid < D) {
    bias_s[tid] = lin_b[layer * D + tid];
    g_s[tid]    = ln_g[layer * D + tid];
    b_s[tid]    = ln_b[layer * D + tid];
  }
  int h0 = h_index[0], h1 = h_index[1];
  __syncthreads();                     // only barrier: weight staging
  int wid = tid >> 6, lane = tid & 63;
  int base = (blockIdx.x * 8 + wid) * 8;
  #pragma unroll 1
  for (int g = 0; g < 2; ++g) {
    int gbase = base + g * 4;
    // prefetch row_ptr for the group: one coalesced load + shuffles
    int rp = 0;
    if (lane <= 4) rp = row_ptr[gbase + lane];
    // ---- gather 4 nodes ----
    #pragma unroll 1
    for (int ni = 0; ni < 4; ++ni) {
      int n = gbase + ni;
      int rs = __shfl(rp, ni), re = __shfl(rp, ni + 1);
      float a0 = 0.f, a1 = 0.f;
      if (first) {
        for (int j = rs; j < re; ++j) {
          unsigned int pk = es[j];
          int s  = (int)(pk & 0xffffu);
          int et = (int)(pk >> 16);
          if (s == h0) { float2 xv = xo[(size_t)s * D + lane];
                         float2 rv = rel2[et * D + lane];
                         a0 = fmaf(xv.x, rv.x, a0); }
          if (s == h1) { float2 xv = xo[(size_t)s * D + lane];
                         float2 rv = rel2[et * D + lane];
                         a1 = fmaf(xv.y, rv.y, a1); }
        }
      } else {
        int j = rs;
        for (; j + 2 <= re; j += 2) {   // 4 independent loads in flight
          unsigned int p0 = es[j], p1 = es[j + 1];
          int s0 = (int)(p0 & 0xffffu), e0 = (int)(p0 >> 16);
          int s1 = (int)(p1 & 0xffffu), e1 = (int)(p1 >> 16);
          float2 xa = xo[(size_t)s0 * D + lane];
          float2 ra = rel2[e0 * D + lane];
          float2 xb = xo[(size_t)s1 * D + lane];
          float2 rb = rel2[e1 * D + lane];
          a0 = fmaf(xa.x, ra.x, a0); a1 = fmaf(xa.y, ra.y, a1);
          a0 = fmaf(xb.x, rb.x, a0); a1 = fmaf(xb.y, rb.y, a1);
        }
        if (j < re) {
          unsigned int pk = es[j];
          int s  = (int)(pk & 0xffffu);
          int et = (int)(pk >> 16);
          float2 xv = xo[(size_t)s * D + lane];
          float2 rv = rel2[et * D + lane];
          a0 = fmaf(xv.x, rv.x, a0); a1 = fmaf(xv.y, rv.y, a1);
        }
      }
      if (n == h0) a0 += q2[lane].x;     // + boundary
      if (n == h1) a1 += q2[lane].y;
      rows[wid][ni][lane] = xo[(size_t)n * D + lane];
      rows[wid][ni][D + lane] = make_float2(a0, a1);
    }
    compiler_fence();   // keep float4 reads below the float2 writes (TBAA)
    // ---- linear for 4 nodes (same-wave LDS RAW: in-order per wave) ----
    float o0[4], o1[4];
    #pragma unroll
    for (int ni = 0; ni < 4; ++ni) { o0[ni] = bias_s[lane]; o1[ni] = o0[ni]; }
    #pragma unroll 4
    for (int k2 = 0; k2 < D; ++k2) {
      float2 wk = wpk[k2][lane];         // 512 B, 2-way alias (free)
      #pragma unroll
      for (int ni = 0; ni < 4; ++ni) {
        float4 rr = ((const float4*)&rows[wid][ni][0])[k2];  // 16 B broadcast
        o0[ni] = fmaf(rr.x, wk.x, o0[ni]); o1[ni] = fmaf(rr.y, wk.x, o1[ni]);
        o0[ni] = fmaf(rr.z, wk.y, o0[ni]); o1[ni] = fmaf(rr.w, wk.y, o1[ni]);
      }
    }
    // ---- LayerNorm + relu + shortcut, 4 nodes ----
    #pragma unroll
    for (int ni = 0; ni < 4; ++ni) {
      int n = gbase + ni;
      float s10 = o0[ni], s20 = o0[ni] * o0[ni];
      float s11 = o1[ni], s21 = o1[ni] * o1[ni];
      #pragma unroll
      for (int m = 32; m > 0; m >>= 1) {
        s10 += __shfl_xor(s10, m); s20 += __shfl_xor(s20, m);
        s11 += __shfl_xor(s11, m); s21 += __shfl_xor(s21, m);
      }
      float mu0 = s10 * (1.f / D), var0 = s20 * (1.f / D) - mu0 * mu0;
      float mu1 = s11 * (1.f / D), var1 = s21 * (1.f / D) - mu1 * mu1;
      float2 xv = rows[wid][ni][lane];
      float r0 = fmaxf((o0[ni] - mu0) * rsqrtf(var0 + EPS) * g_s[lane] + b_s[lane], 0.f) + xv.x;
      float r1 = fmaxf((o1[ni] - mu1) * rsqrtf(var1 + EPS) * g_s[lane] + b_s[lane], 0.f) + xv.y;
      xn[(size_t)n * D + lane] = make_float2(r0, r1);
    }
  }
}

__device__ __forceinline__ unsigned int pack_bf2(float lo, float hi) {
  unsigned int ulo = (__float_as_uint(lo) + 0x8000u) >> 16;
  unsigned int uhi = (__float_as_uint(hi) + 0x8000u) & 0xffff0000u;
  return (ulo & 0xffffu) | uhi;
}

// ---- final MLP: relu(concat(x, query) @ mlp_w + mlp_b) -> fp32 out ----
// 4-node groups; weights packed bf16 (col-pair x k-pair); query half shared.
__global__ __launch_bounds__(512, 4) void k_mlp(
    const float2* __restrict__ x2, const float2* __restrict__ q2,
    const float* __restrict__ mlp_w,            // [2D][2D] row-major fp32
    const float* __restrict__ mlp_b,
    float2* __restrict__ out) {
  __shared__ uint2 wpk[D][D];        // [k2][colpair]: .x = k=2k2, .y = k=2k2+1; 32 KB
  __shared__ float2 rowsx[8][4][D];  // x half per wave/node; 16 KB
  __shared__ float2 q2s[D];          // query half (b0,b1)
  int tid = threadIdx.x;
  for (int i = tid; i < D * D; i += 512) {
    int k2 = i >> 6, jp = i & 63;
    const float* w0 = mlp_w + (size_t)(2 * k2) * 2 * D;
    const float* w1 = mlp_w + (size_t)(2 * k2 + 1) * 2 * D;
    wpk[k2][jp] = make_uint2(pack_bf2(w0[2 * jp], w0[2 * jp + 1]),
                             pack_bf2(w1[2 * jp], w1[2 * jp + 1]));
  }
  if (tid < D) q2s[tid] = q2[tid];
  __syncthreads();
  int wid = tid >> 6, lane = tid & 63;
  float b0 = mlp_b[2 * lane], b1 = mlp_b[2 * lane + 1];
  int base = (blockIdx.x * 8 + wid) * 8;
  #pragma unroll 1
  for (int g = 0; g < 2; ++g) {
    int gbase = base + g * 4;
    #pragma unroll
    for (int ni = 0; ni < 4; ++ni)
      rowsx[wid][ni][lane] = x2[(size_t)(gbase + ni) * D + lane];
    compiler_fence();   // keep float4 reads below the float2 writes (TBAA)
    float a00[4], a01[4], a10[4], a11[4];
    #pragma unroll
    for (int ni = 0; ni < 4; ++ni) { a00[ni] = b0; a01[ni] = b1; a10[ni] = b0; a11[ni] = b1; }
    #pragma unroll 4
    for (int k2 = 0; k2 < D / 2; ++k2) {      // x half: k = 2k2, 2k2+1 in [0,64)
      uint2 wv = wpk[k2][lane];
      float w00 = __uint_as_float(wv.x << 16);
      float w01 = __uint_as_float(wv.x & 0xffff0000u);
      float w10 = __uint_as_float(wv.y << 16);
      float w11 = __uint_as_float(wv.y & 0xffff0000u);
      #pragma unroll
      for (int ni = 0; ni < 4; ++ni) {
        float4 rr = ((const float4*)&rowsx[wid][ni][0])[k2];  // (k even b0,b1, k odd b0,b1)
        a00[ni] = fmaf(rr.x, w00, a00[ni]); a01[ni] = fmaf(rr.x, w01, a01[ni]);
        a10[ni] = fmaf(rr.y, w00, a10[ni]); a11[ni] = fmaf(rr.y, w01, a11[ni]);
        a00[ni] = fmaf(rr.z, w10, a00[ni]); a01[ni] = fmaf(rr.z, w11, a01[ni]);
        a10[ni] = fmaf(rr.w, w10, a10[ni]); a11[ni] = fmaf(rr.w, w11, a11[ni]);
      }
    }
    #pragma unroll 4
    for (int k2 = D / 2; k2 < D; ++k2) {      // query half: shared across nodes
      uint2 wv = wpk[k2][lane];
      float w00 = __uint_as_float(wv.x << 16);
      float w01 = __uint_as_float(wv.x & 0xffff0000u);
      float w10 = __uint_as_float(wv.y << 16);
      float w11 = __uint_as_float(wv.y & 0xffff0000u);
      float4 qq = ((const float4*)q2s)[k2 - D / 2];
      #pragma unroll
      for (int ni = 0; ni < 4; ++ni) {
        a00[ni] = fmaf(qq.x, w00, a00[ni]); a01[ni] = fmaf(qq.x, w01, a01[ni]);
        a10[ni] = fmaf(qq.y, w00, a10[ni]); a11[ni] = fmaf(qq.y, w01, a11[ni]);
        a00[ni] = fmaf(qq.z, w10, a00[ni]); a01[ni] = fmaf(qq.z, w11, a01[ni]);
        a10[ni] = fmaf(qq.w, w10, a10[ni]); a11[ni] = fmaf(qq.w, w11, a11[ni]);
      }
    }
    #pragma unroll
    for (int ni = 0; ni < 4; ++ni) {
      int n = gbase + ni;
      out[(size_t)n * D + lane] = make_float2(fmaxf(a00[ni], 0.f), fmaxf(a01[ni], 0.f));
      out[((size_t)N + n) * D + lane] = make_float2(fmaxf(a10[ni], 0.f), fmaxf(a11[ni], 0.f));
    }
  }
}

}  // namespace

extern "C" void kernel_launch(void* const* d_in, const int* in_sizes, int n_in,
                              void* d_out, int out_size, void* d_ws, size_t ws_size,
                              hipStream_t stream) {
  const float* rel_reps = (const float*)d_in[0];
  const int* h_index    = (const int*)d_in[1];
  const int* r_index    = (const int*)d_in[2];
  const int* edge_index = (const int*)d_in[3];
  const int* edge_type  = (const int*)d_in[4];
  const float* proj_w1  = (const float*)d_in[5];
  const float* proj_b1  = (const float*)d_in[6];
  const float* proj_w2  = (const float*)d_in[7];
  const float* proj_b2  = (const float*)d_in[8];
  const float* lin_w    = (const float*)d_in[9];
  const float* lin_b    = (const float*)d_in[10];
  const float* ln_g     = (const float*)d_in[11];
  const float* ln_b     = (const float*)d_in[12];
  const float* mlp_w    = (const float*)d_in[13];
  const float* mlp_b    = (const float*)d_in[14];

  // workspace (floats): x0 | x1 | rel_all | query | cnt | row_ptr | cursor | es | bsum
  float* x0      = (float*)d_ws;                       // N*D float2
  float* x1      = x0 + (size_t)2 * N * D;
  float* rel_all = x1 + (size_t)2 * N * D;             // L*R*D float2
  float* query   = rel_all + (size_t)2 * L * R * D;    // D float2
  int*   cnt     = (int*)(query + 2 * D);
  int*   row_ptr = cnt + N;
  int*   cursor  = row_ptr + (N + 1);
  unsigned int* es = (unsigned int*)(cursor + N);
  int*   bsum    = (int*)(es + E);

  const int* srcp = edge_index;
  const int* dstp = edge_index + E;

  hipMemsetAsync(x0, 0, (size_t)2 * N * D * sizeof(float), stream);
  hipMemsetAsync(cnt, 0, N * sizeof(int), stream);
  k_init<<<1, 128, 0, stream>>>(rel_reps, h_index, r_index, x0, query);
  k_rel<<<L * B * R, 64, 0, stream>>>(rel_reps, proj_w1, proj_b1, proj_w2, proj_b2, rel_all);
  k_hist<<<EB, 256, 0, stream>>>(dstp, cnt);           // EDGE grid (R4 bug: was NB)
  k_scan1<<<NB, 256, 0, stream>>>(cnt, row_ptr, bsum);
  k_scan2<<<1, 256, 0, stream>>>(bsum, row_ptr);
  k_scan3<<<NB, 256, 0, stream>>>(row_ptr, bsum, cursor);
  k_fill<<<EB, 256, 0, stream>>>(srcp, dstp, edge_type, cursor, es);

  float* xo = x0;
  float* xn = x1;
  for (int l = 0; l < L; ++l) {
    k_layer<<<N / 64, 512, 0, stream>>>((const float2*)xo, (float2*)xn,
                                        (const float2*)(rel_all + (size_t)2 * l * R * D),
                                        row_ptr, es, (const float2*)query, h_index,
                                        lin_w, lin_b, ln_g, ln_b, l, (l == 0) ? 1 : 0);
    float* t = xo; xo = xn; xn = t;
  }
  k_mlp<<<N / 64, 512, 0, stream>>>((const float2*)xo, (const float2*)query,
                                    mlp_w, mlp_b, (float2*)d_out);
}

// Round 7
// 652.825 us; speedup vs baseline: 1.1835x; 1.1835x over previous
//
#include <hip/hip_runtime.h>
#include <hip/hip_bf16.h>

namespace {

constexpr int B = 2;
constexpr int N = 40000;
constexpr int E = 400000;
constexpr int R = 64;
constexpr int D = 64;
constexpr int L = 6;
constexpr float EPS = 1e-5f;
constexpr int NB = (N + 255) / 256;   // 157 node-grid blocks
constexpr int EB = (E + 255) / 256;   // 1563 edge-grid blocks

// Compiler-only memory barrier: blocks TBAA-based reordering of the
// float4-cast LDS reads above the float2-typed LDS writes.
__device__ __forceinline__ void compiler_fence() { asm volatile("" ::: "memory"); }

// Batch-interleaved layout: float2 element = (batch0, batch1).

// ---- query gather + boundary scatter (x must be pre-zeroed) ----
__global__ void k_init(const float* __restrict__ rel_reps,
                       const int* __restrict__ h_index, const int* __restrict__ r_index,
                       float* __restrict__ x_f, float* __restrict__ query_f) {
  int t = threadIdx.x;           // 128 threads
  int b = t >> 6, d = t & 63;
  float q = rel_reps[(b * R + r_index[b]) * D + d];
  query_f[d * 2 + b] = q;
  x_f[((size_t)h_index[b] * D + d) * 2 + b] = q;
}

// ---- relation projection MLP for all layers: rel2[l][r*64+d] = (b0, b1) ----
__global__ __launch_bounds__(64) void k_rel(
    const float* __restrict__ rel_reps,
    const float* __restrict__ pw1, const float* __restrict__ pb1,
    const float* __restrict__ pw2, const float* __restrict__ pb2,
    float* __restrict__ rel_f) {
  __shared__ float row[D];
  __shared__ float row2[D];
  int idx = blockIdx.x;             // [0, L*B*R)
  int l = idx / (B * R);
  int br = idx - l * (B * R);       // b*R + r
  int b = br / R, r = br - b * R;
  int d = threadIdx.x;
  row[d] = rel_reps[(size_t)br * D + d];
  __syncthreads();
  const float* w1 = pw1 + (size_t)l * D * D;
  float acc = pb1[l * D + d];
  for (int k = 0; k < D; ++k) acc = fmaf(row[k], w1[k * D + d], acc);
  row2[d] = fmaxf(acc, 0.f);
  __syncthreads();
  const float* w2 = pw2 + (size_t)l * D * D;
  float acc2 = pb2[l * D + d];
  for (int k = 0; k < D; ++k) acc2 = fmaf(row2[k], w2[k * D + d], acc2);
  rel_f[(((size_t)l * R + r) * D + d) * 2 + b] = acc2;
}

// ---- CSR build ----
__global__ __launch_bounds__(256) void k_hist(const int* __restrict__ dst,
                                              int* __restrict__ cnt) {
  int e = blockIdx.x * 256 + threadIdx.x;
  if (e < E) atomicAdd(&cnt[dst[e]], 1);
}

__global__ __launch_bounds__(256) void k_scan1(const int* __restrict__ cnt,
                                               int* __restrict__ row_ptr,
                                               int* __restrict__ bsum) {
  __shared__ int s[256];
  int t = threadIdx.x;
  int i = blockIdx.x * 256 + t;
  int v = (i < N) ? cnt[i] : 0;
  s[t] = v;
  __syncthreads();
  #pragma unroll
  for (int off = 1; off < 256; off <<= 1) {   // Hillis-Steele inclusive
    int u = (t >= off) ? s[t - off] : 0;
    __syncthreads();
    s[t] += u;
    __syncthreads();
  }
  if (i < N) row_ptr[i] = s[t] - v;           // exclusive-in-block
  if (t == 255) bsum[blockIdx.x] = s[255];
}

__global__ __launch_bounds__(256) void k_scan2(int* __restrict__ bsum,
                                               int* __restrict__ row_ptr) {
  __shared__ int s[NB];
  int t = threadIdx.x;
  if (t < NB) s[t] = bsum[t];
  __syncthreads();
  if (t == 0) {
    int run = 0;
    for (int i = 0; i < NB; ++i) { int v = s[i]; s[i] = run; run += v; }
    row_ptr[N] = run;                         // = E
  }
  __syncthreads();
  if (t < NB) bsum[t] = s[t];
}

__global__ __launch_bounds__(256) void k_scan3(int* __restrict__ row_ptr,
                                               const int* __restrict__ bsum,
                                               int* __restrict__ cursor) {
  int i = blockIdx.x * 256 + threadIdx.x;
  if (i < N) {
    int v = row_ptr[i] + bsum[blockIdx.x];
    row_ptr[i] = v;
    cursor[i] = v;
  }
}

__global__ __launch_bounds__(256) void k_fill(const int* __restrict__ src,
                                              const int* __restrict__ dst,
                                              const int* __restrict__ etype,
                                              int* __restrict__ cursor,
                                              unsigned int* __restrict__ es) {
  int e = blockIdx.x * 256 + threadIdx.x;
  if (e < E) {
    int p = atomicAdd(&cursor[dst[e]], 1);
    es[p] = (unsigned int)src[e] | ((unsigned int)etype[e] << 16);  // src < 65536
  }
}

// ---- gather: one wave per node, zero LDS, 32 waves/CU ----
// Edge list fetched in ONE coalesced lane-indexed load (deg<=64 fast path),
// broadcast via shuffles; x/rel loads unrolled x4 (8 loads in flight).
// Writes agg (+boundary) into the ping-pong target buffer.
__global__ __launch_bounds__(256, 8) void k_gather(
    const float2* __restrict__ xo, float2* __restrict__ agg,
    const float2* __restrict__ rel2,             // [R*64] float2, this layer
    const int* __restrict__ row_ptr, const unsigned int* __restrict__ es,
    const float2* __restrict__ q2, const int* __restrict__ h_index, int first) {
  int lane = threadIdx.x & 63;
  int n = (blockIdx.x * 256 + threadIdx.x) >> 6;   // node; grid covers N exactly
  int h0 = h_index[0], h1 = h_index[1];
  int rs = row_ptr[n], re = row_ptr[n + 1];
  int deg = re - rs;
  int m = min(deg, 64);
  unsigned int pkl = 0;
  if (lane < m) pkl = es[rs + lane];               // whole edge list, one load
  float a0 = 0.f, a1 = 0.f;
  if (first) {
    // layer 0: x nonzero only at h0 (.x) and h1 (.y); skip other edges
    for (int j = 0; j < m; ++j) {
      unsigned int pk = __shfl(pkl, j);
      int s  = (int)(pk & 0xffffu);
      int et = (int)(pk >> 16);
      if (s == h0) { a0 = fmaf(xo[(size_t)s * D + lane].x, rel2[et * D + lane].x, a0); }
      if (s == h1) { a1 = fmaf(xo[(size_t)s * D + lane].y, rel2[et * D + lane].y, a1); }
    }
    for (int j = rs + 64; j < re; ++j) {           // deg>64 overflow (rare)
      unsigned int pk = es[j];
      int s  = (int)(pk & 0xffffu);
      int et = (int)(pk >> 16);
      if (s == h0) { a0 = fmaf(xo[(size_t)s * D + lane].x, rel2[et * D + lane].x, a0); }
      if (s == h1) { a1 = fmaf(xo[(size_t)s * D + lane].y, rel2[et * D + lane].y, a1); }
    }
  } else {
    int j = 0;
    for (; j + 4 <= m; j += 4) {                   // 8 independent loads in flight
      unsigned int p0 = __shfl(pkl, j),     p1 = __shfl(pkl, j + 1);
      unsigned int p2 = __shfl(pkl, j + 2), p3 = __shfl(pkl, j + 3);
      float2 xa = xo[(size_t)(p0 & 0xffffu) * D + lane];
      float2 ra = rel2[(p0 >> 16) * D + lane];
      float2 xb = xo[(size_t)(p1 & 0xffffu) * D + lane];
      float2 rb = rel2[(p1 >> 16) * D + lane];
      float2 xc = xo[(size_t)(p2 & 0xffffu) * D + lane];
      float2 rc = rel2[(p2 >> 16) * D + lane];
      float2 xd = xo[(size_t)(p3 & 0xffffu) * D + lane];
      float2 rd = rel2[(p3 >> 16) * D + lane];
      a0 = fmaf(xa.x, ra.x, a0); a1 = fmaf(xa.y, ra.y, a1);
      a0 = fmaf(xb.x, rb.x, a0); a1 = fmaf(xb.y, rb.y, a1);
      a0 = fmaf(xc.x, rc.x, a0); a1 = fmaf(xc.y, rc.y, a1);
      a0 = fmaf(xd.x, rd.x, a0); a1 = fmaf(xd.y, rd.y, a1);
    }
    for (; j < m; ++j) {
      unsigned int pk = __shfl(pkl, j);
      float2 xv = xo[(size_t)(pk & 0xffffu) * D + lane];
      float2 rv = rel2[(pk >> 16) * D + lane];
      a0 = fmaf(xv.x, rv.x, a0); a1 = fmaf(xv.y, rv.y, a1);
    }
    for (int jj = rs + 64; jj < re; ++jj) {        // deg>64 overflow (rare)
      unsigned int pk = es[jj];
      float2 xv = xo[(size_t)(pk & 0xffffu) * D + lane];
      float2 rv = rel2[(pk >> 16) * D + lane];
      a0 = fmaf(xv.x, rv.x, a0); a1 = fmaf(xv.y, rv.y, a1);
    }
  }
  if (n == h0) a0 += q2[lane].x;                   // + boundary
  if (n == h1) a1 += q2[lane].y;
  agg[(size_t)n * D + lane] = make_float2(a0, a1);
}

// ---- linear + LN + relu + shortcut, in place on the agg buffer ----
// 512 threads = 8 waves; 8 nodes/wave as 2 groups of 4; streaming reads.
__global__ __launch_bounds__(512) void k_linear(
    const float2* __restrict__ xo, float2* __restrict__ xn,   // xn holds agg on entry
    const float* __restrict__ lin_w, const float* __restrict__ lin_b,
    const float* __restrict__ ln_g, const float* __restrict__ ln_b,
    int layer) {
  __shared__ float2 wpk[D][D];         // wpk[k2][out] = (w[2k2][out], w[2k2+1][out]), 32 KB
  __shared__ float bias_s[D], g_s[D], b_s[D];
  __shared__ float2 rows[8][4][2 * D]; // per-wave, 4 nodes, concat row; 32 KB
  int tid = threadIdx.x;
  const float* lw = lin_w + (size_t)layer * 2 * D * D;
  for (int i = tid; i < D * D; i += 512) {
    int k2 = i >> 6, out = i & 63;
    wpk[k2][out] = make_float2(lw[(2 * k2) * D + out], lw[(2 * k2 + 1) * D + out]);
  }
  if (tid < D) {
    bias_s[tid] = lin_b[layer * D + tid];
    g_s[tid]    = ln_g[layer * D + tid];
    b_s[tid]    = ln_b[layer * D + tid];
  }
  __syncthreads();                     // weight staging
  int wid = tid >> 6, lane = tid & 63;
  int base = (blockIdx.x * 8 + wid) * 8;
  #pragma unroll 1
  for (int g = 0; g < 2; ++g) {
    int gbase = base + g * 4;
    #pragma unroll
    for (int ni = 0; ni < 4; ++ni) {
      int n = gbase + ni;
      rows[wid][ni][lane]     = xo[(size_t)n * D + lane];
      rows[wid][ni][D + lane] = xn[(size_t)n * D + lane];   // agg
    }
    compiler_fence();   // keep float4 reads below the float2 writes (TBAA)
    float o0[4], o1[4];
    #pragma unroll
    for (int ni = 0; ni < 4; ++ni) { o0[ni] = bias_s[lane]; o1[ni] = o0[ni]; }
    #pragma unroll 4
    for (int k2 = 0; k2 < D; ++k2) {
      float2 wk = wpk[k2][lane];
      #pragma unroll
      for (int ni = 0; ni < 4; ++ni) {
        float4 rr = ((const float4*)&rows[wid][ni][0])[k2];  // 16 B broadcast
        o0[ni] = fmaf(rr.x, wk.x, o0[ni]); o1[ni] = fmaf(rr.y, wk.x, o1[ni]);
        o0[ni] = fmaf(rr.z, wk.y, o0[ni]); o1[ni] = fmaf(rr.w, wk.y, o1[ni]);
      }
    }
    #pragma unroll
    for (int ni = 0; ni < 4; ++ni) {
      int n = gbase + ni;
      float s10 = o0[ni], s20 = o0[ni] * o0[ni];
      float s11 = o1[ni], s21 = o1[ni] * o1[ni];
      #pragma unroll
      for (int m = 32; m > 0; m >>= 1) {
        s10 += __shfl_xor(s10, m); s20 += __shfl_xor(s20, m);
        s11 += __shfl_xor(s11, m); s21 += __shfl_xor(s21, m);
      }
      float mu0 = s10 * (1.f / D), var0 = s20 * (1.f / D) - mu0 * mu0;
      float mu1 = s11 * (1.f / D), var1 = s21 * (1.f / D) - mu1 * mu1;
      float2 xv = rows[wid][ni][lane];
      float r0 = fmaxf((o0[ni] - mu0) * rsqrtf(var0 + EPS) * g_s[lane] + b_s[lane], 0.f) + xv.x;
      float r1 = fmaxf((o1[ni] - mu1) * rsqrtf(var1 + EPS) * g_s[lane] + b_s[lane], 0.f) + xv.y;
      xn[(size_t)n * D + lane] = make_float2(r0, r1);   // in place: row owned by this wave
    }
  }
}

__device__ __forceinline__ unsigned int pack_bf2(float lo, float hi) {
  unsigned int ulo = (__float_as_uint(lo) + 0x8000u) >> 16;
  unsigned int uhi = (__float_as_uint(hi) + 0x8000u) & 0xffff0000u;
  return (ulo & 0xffffu) | uhi;
}

// ---- final MLP: relu(concat(x, query) @ mlp_w + mlp_b) -> fp32 out ----
__global__ __launch_bounds__(512) void k_mlp(
    const float2* __restrict__ x2, const float2* __restrict__ q2,
    const float* __restrict__ mlp_w,            // [2D][2D] row-major fp32
    const float* __restrict__ mlp_b,
    float2* __restrict__ out) {
  __shared__ uint2 wpk[D][D];        // [k2][colpair]: .x = k=2k2, .y = k=2k2+1; 32 KB
  __shared__ float2 rowsx[8][4][D];  // x half per wave/node; 16 KB
  __shared__ float2 q2s[D];          // query half (b0,b1)
  int tid = threadIdx.x;
  for (int i = tid; i < D * D; i += 512) {
    int k2 = i >> 6, jp = i & 63;
    const float* w0 = mlp_w + (size_t)(2 * k2) * 2 * D;
    const float* w1 = mlp_w + (size_t)(2 * k2 + 1) * 2 * D;
    wpk[k2][jp] = make_uint2(pack_bf2(w0[2 * jp], w0[2 * jp + 1]),
                             pack_bf2(w1[2 * jp], w1[2 * jp + 1]));
  }
  if (tid < D) q2s[tid] = q2[tid];
  __syncthreads();
  int wid = tid >> 6, lane = tid & 63;
  float b0 = mlp_b[2 * lane], b1 = mlp_b[2 * lane + 1];
  int base = (blockIdx.x * 8 + wid) * 8;
  #pragma unroll 1
  for (int g = 0; g < 2; ++g) {
    int gbase = base + g * 4;
    #pragma unroll
    for (int ni = 0; ni < 4; ++ni)
      rowsx[wid][ni][lane] = x2[(size_t)(gbase + ni) * D + lane];
    compiler_fence();
    float a00[4], a01[4], a10[4], a11[4];
    #pragma unroll
    for (int ni = 0; ni < 4; ++ni) { a00[ni] = b0; a01[ni] = b1; a10[ni] = b0; a11[ni] = b1; }
    #pragma unroll 4
    for (int k2 = 0; k2 < D / 2; ++k2) {      // x half
      uint2 wv = wpk[k2][lane];
      float w00 = __uint_as_float(wv.x << 16);
      float w01 = __uint_as_float(wv.x & 0xffff0000u);
      float w10 = __uint_as_float(wv.y << 16);
      float w11 = __uint_as_float(wv.y & 0xffff0000u);
      #pragma unroll
      for (int ni = 0; ni < 4; ++ni) {
        float4 rr = ((const float4*)&rowsx[wid][ni][0])[k2];
        a00[ni] = fmaf(rr.x, w00, a00[ni]); a01[ni] = fmaf(rr.x, w01, a01[ni]);
        a10[ni] = fmaf(rr.y, w00, a10[ni]); a11[ni] = fmaf(rr.y, w01, a11[ni]);
        a00[ni] = fmaf(rr.z, w10, a00[ni]); a01[ni] = fmaf(rr.z, w11, a01[ni]);
        a10[ni] = fmaf(rr.w, w10, a10[ni]); a11[ni] = fmaf(rr.w, w11, a11[ni]);
      }
    }
    #pragma unroll 4
    for (int k2 = D / 2; k2 < D; ++k2) {      // query half: shared across nodes
      uint2 wv = wpk[k2][lane];
      float w00 = __uint_as_float(wv.x << 16);
      float w01 = __uint_as_float(wv.x & 0xffff0000u);
      float w10 = __uint_as_float(wv.y << 16);
      float w11 = __uint_as_float(wv.y & 0xffff0000u);
      float4 qq = ((const float4*)q2s)[k2 - D / 2];
      #pragma unroll
      for (int ni = 0; ni < 4; ++ni) {
        a00[ni] = fmaf(qq.x, w00, a00[ni]); a01[ni] = fmaf(qq.x, w01, a01[ni]);
        a10[ni] = fmaf(qq.y, w00, a10[ni]); a11[ni] = fmaf(qq.y, w01, a11[ni]);
        a00[ni] = fmaf(qq.z, w10, a00[ni]); a01[ni] = fmaf(qq.z, w11, a01[ni]);
        a10[ni] = fmaf(qq.w, w10, a10[ni]); a11[ni] = fmaf(qq.w, w11, a11[ni]);
      }
    }
    #pragma unroll
    for (int ni = 0; ni < 4; ++ni) {
      int n = gbase + ni;
      out[(size_t)n * D + lane] = make_float2(fmaxf(a00[ni], 0.f), fmaxf(a01[ni], 0.f));
      out[((size_t)N + n) * D + lane] = make_float2(fmaxf(a10[ni], 0.f), fmaxf(a11[ni], 0.f));
    }
  }
}

}  // namespace

extern "C" void kernel_launch(void* const* d_in, const int* in_sizes, int n_in,
                              void* d_out, int out_size, void* d_ws, size_t ws_size,
                              hipStream_t stream) {
  const float* rel_reps = (const float*)d_in[0];
  const int* h_index    = (const int*)d_in[1];
  const int* r_index    = (const int*)d_in[2];
  const int* edge_index = (const int*)d_in[3];
  const int* edge_type  = (const int*)d_in[4];
  const float* proj_w1  = (const float*)d_in[5];
  const float* proj_b1  = (const float*)d_in[6];
  const float* proj_w2  = (const float*)d_in[7];
  const float* proj_b2  = (const float*)d_in[8];
  const float* lin_w    = (const float*)d_in[9];
  const float* lin_b    = (const float*)d_in[10];
  const float* ln_g     = (const float*)d_in[11];
  const float* ln_b     = (const float*)d_in[12];
  const float* mlp_w    = (const float*)d_in[13];
  const float* mlp_b    = (const float*)d_in[14];

  // workspace (floats): x0 | x1 | rel_all | query | cnt | row_ptr | cursor | es | bsum
  float* x0      = (float*)d_ws;                       // N*D float2
  float* x1      = x0 + (size_t)2 * N * D;
  float* rel_all = x1 + (size_t)2 * N * D;             // L*R*D float2
  float* query   = rel_all + (size_t)2 * L * R * D;    // D float2
  int*   cnt     = (int*)(query + 2 * D);
  int*   row_ptr = cnt + N;
  int*   cursor  = row_ptr + (N + 1);
  unsigned int* es = (unsigned int*)(cursor + N);
  int*   bsum    = (int*)(es + E);

  const int* srcp = edge_index;
  const int* dstp = edge_index + E;

  hipMemsetAsync(x0, 0, (size_t)2 * N * D * sizeof(float), stream);
  hipMemsetAsync(cnt, 0, N * sizeof(int), stream);
  k_init<<<1, 128, 0, stream>>>(rel_reps, h_index, r_index, x0, query);
  k_rel<<<L * B * R, 64, 0, stream>>>(rel_reps, proj_w1, proj_b1, proj_w2, proj_b2, rel_all);
  k_hist<<<EB, 256, 0, stream>>>(dstp, cnt);
  k_scan1<<<NB, 256, 0, stream>>>(cnt, row_ptr, bsum);
  k_scan2<<<1, 256, 0, stream>>>(bsum, row_ptr);
  k_scan3<<<NB, 256, 0, stream>>>(row_ptr, bsum, cursor);
  k_fill<<<EB, 256, 0, stream>>>(srcp, dstp, edge_type, cursor, es);

  float* xo = x0;
  float* xn = x1;
  for (int l = 0; l < L; ++l) {
    // gather writes agg into xn; linear updates xn in place
    k_gather<<<N / 4, 256, 0, stream>>>((const float2*)xo, (float2*)xn,
                                        (const float2*)(rel_all + (size_t)2 * l * R * D),
                                        row_ptr, es, (const float2*)query, h_index,
                                        (l == 0) ? 1 : 0);
    k_linear<<<N / 64, 512, 0, stream>>>((const float2*)xo, (float2*)xn,
                                         lin_w, lin_b, ln_g, ln_b, l);
    float* t = xo; xo = xn; xn = t;
  }
  k_mlp<<<N / 64, 512, 0, stream>>>((const float2*)xo, (const float2*)query,
                                    mlp_w, mlp_b, (float2*)d_out);
}